// Round 7
// baseline (2712.492 us; speedup 1.0000x reference)
//
#include <hip/hip_runtime.h>
#include <stdint.h>

#define B_ 32
#define T_ 256
#define E_ 1024
#define H_ 1024
#define V_ 32000

typedef unsigned short u16;
typedef unsigned int   u32;
typedef unsigned long long u64;

typedef __attribute__((ext_vector_type(8))) short bf16x8;
typedef __attribute__((ext_vector_type(4))) float f32x4;

__device__ __forceinline__ float bf2f(u16 u){ u32 x = ((u32)u) << 16; return __uint_as_float(x); }
__device__ __forceinline__ u16  f2bf(float f){
  u32 x = __float_as_uint(f);
  u32 r = (x + 0x7fffu + ((x >> 16) & 1u)) >> 16;
  return (u16)r;
}
__device__ __forceinline__ float fsig(float x){ return 1.f / (1.f + __expf(-x)); }
__device__ __forceinline__ float ftanh(float x){
  float e = __expf(2.f * x);
  return 1.f - 2.f / (e + 1.f);
}
__device__ __forceinline__ u32 umin2(u32 a, u32 b){ return a < b ? a : b; }

__device__ __forceinline__ void gload_lds16(const void* g, void* l){
  __builtin_amdgcn_global_load_lds((const __attribute__((address_space(1))) unsigned int*)g,
                                   (__attribute__((address_space(3))) unsigned int*)l, 16, 0, 0);
}

// ---------------- prep kernels ----------------
__global__ void k_prep_wc(const float* __restrict__ wih, const float* __restrict__ whh,
                          u16* __restrict__ Wc){
  int i = blockIdx.x * 256 + threadIdx.x;
  int r = i >> 9; int k4 = (i & 511) << 2;
  const float* src = (k4 < 1024) ? (wih + (size_t)r * 1024 + k4)
                                 : (whh + (size_t)r * 1024 + (k4 - 1024));
  float4 v = *(const float4*)src;
  u64 pk = (u64)f2bf(v.x) | ((u64)f2bf(v.y) << 16) | ((u64)f2bf(v.z) << 32) | ((u64)f2bf(v.w) << 48);
  *(u64*)(Wc + (size_t)r * 2048 + k4) = pk;
}

__global__ void k_prep_ew(const float* __restrict__ src, u16* __restrict__ dst){
  size_t i = (size_t)(blockIdx.x * 256 + threadIdx.x) * 4;
  float4 v = *(const float4*)(src + i);
  u64 pk = (u64)f2bf(v.x) | ((u64)f2bf(v.y) << 16) | ((u64)f2bf(v.z) << 32) | ((u64)f2bf(v.w) << 48);
  *(u64*)(dst + i) = pk;
}

__global__ void k_prep_bsum(const float* __restrict__ bih, const float* __restrict__ bhh,
                            float* __restrict__ bsum){
  int i = blockIdx.x * 256 + threadIdx.x;
  bsum[i] = bih[i] + bhh[i];
}

__global__ void k_gather_x(const int* __restrict__ words, const float* __restrict__ embed,
                           u16* __restrict__ X){
  int row = blockIdx.x;                         // t*32 + b
  int t = row >> 5, b = row & 31;
  int wd = words[b * T_ + t];
  const float* src = embed + (size_t)wd * E_;
  u16* dst = X + (size_t)row * E_;
  int e = threadIdx.x * 4;
  float4 v = *(const float4*)(src + e);
  u64 pk = (u64)f2bf(v.x) | ((u64)f2bf(v.y) << 16) | ((u64)f2bf(v.z) << 32) | ((u64)f2bf(v.w) << 48);
  *(u64*)(dst + e) = pk;
}

// ---------------- shared 256x128 GEMM tile core, DOUBLE-BUFFERED ----------------
// A: 256 rows, stride 1024 u16. B: 128 rows, stride (1<<blog2) u16. K = 1024.
// LDS: buf[p] at sm + p*24576 (As 16K + Bs 8K). Counted vmcnt(3) keeps the next
// K-step's 3 global_load_lds in flight across the raw barriers (T3/T4 minimum).
__device__ __forceinline__ void stage_tile(const u16* __restrict__ Ab, const u16* __restrict__ Bb,
                                           int blog2, char* buf, int kk, int tid){
  char* As = buf;
  char* Bs = buf + 16384;
  int u0 = tid, r0 = u0 >> 2, s0 = (u0 & 3) ^ ((r0 >> 1) & 3);
  gload_lds16(Ab + (((size_t)r0) << 10) + kk * 32 + s0 * 8, As + (size_t)u0 * 16);
  int u1 = 512 + tid, r1 = u1 >> 2, s1 = (u1 & 3) ^ ((r1 >> 1) & 3);
  gload_lds16(Ab + (((size_t)r1) << 10) + kk * 32 + s1 * 8, As + (size_t)u1 * 16);
  int r2 = tid >> 2, s2 = (tid & 3) ^ ((r2 >> 1) & 3);
  gload_lds16(Bb + (((size_t)r2) << blog2) + kk * 32 + s2 * 8, Bs + (size_t)tid * 16);
}

__device__ __forceinline__ void tile_gemm(const u16* __restrict__ Ab, const u16* __restrict__ Bb,
                                          int blog2, char* sm, f32x4 (&acc)[4][4],
                                          int tid, int lane, int wr, int wc){
  stage_tile(Ab, Bb, blog2, sm, 0, tid);
  #pragma unroll 2
  for (int kk = 0; kk < 32; ++kk){
    char* cur = sm + (size_t)(kk & 1) * 24576;
    if (kk < 31){
      stage_tile(Ab, Bb, blog2, sm + (size_t)((kk + 1) & 1) * 24576, kk + 1, tid);
      asm volatile("s_waitcnt vmcnt(3)" ::: "memory");
    } else {
      asm volatile("s_waitcnt vmcnt(0)" ::: "memory");
    }
    __builtin_amdgcn_s_barrier();
    __builtin_amdgcn_sched_barrier(0);
    char* As = cur;
    char* Bs = cur + 16384;
    bf16x8 af[4], bfr[4];
    #pragma unroll
    for (int mi = 0; mi < 4; ++mi){
      int r = wr * 64 + mi * 16 + (lane & 15);
      u32 byte = ((u32)r << 6) + (((u32)lane >> 4) << 4);
      byte ^= (u32)(r & 6) << 3;
      af[mi] = *(const bf16x8*)(As + byte);
    }
    #pragma unroll
    for (int ni = 0; ni < 4; ++ni){
      int r = wc * 64 + ni * 16 + (lane & 15);
      u32 byte = ((u32)r << 6) + (((u32)lane >> 4) << 4);
      byte ^= (u32)(r & 6) << 3;
      bfr[ni] = *(const bf16x8*)(Bs + byte);
    }
    #pragma unroll
    for (int mi = 0; mi < 4; ++mi)
      #pragma unroll
      for (int ni = 0; ni < 4; ++ni)
        acc[mi][ni] = __builtin_amdgcn_mfma_f32_16x16x32_bf16(af[mi], bfr[ni], acc[mi][ni], 0, 0, 0);
    __builtin_amdgcn_s_barrier();   // protect cur before it is restaged at kk+2
  }
}

// ---------------- k_xgemm: Xg (COL-MAJOR [4096][8192]) = X @ Wih^T + bsum -----------
__launch_bounds__(512, 2)
__global__ void k_xgemm(const u16* __restrict__ X, const u16* __restrict__ Wc,
                        const float* __restrict__ bsum, u16* __restrict__ Xg){
  __shared__ __align__(16) char smem[49152];
  const int tid = threadIdx.x, lane = tid & 63, w = tid >> 6;
  const int wr = w >> 1, wc = w & 1;
  const int mtx = blockIdx.x >> 5, vcx = blockIdx.x & 31;
  const u16* Ab = X + (size_t)mtx * 256 * 1024;
  const u16* Bb = Wc + (size_t)vcx * 128 * 2048;
  f32x4 acc[4][4];
  #pragma unroll
  for (int mi = 0; mi < 4; ++mi)
    #pragma unroll
    for (int ni = 0; ni < 4; ++ni){ f32x4 z = {0.f,0.f,0.f,0.f}; acc[mi][ni] = z; }
  tile_gemm(Ab, Bb, 11, smem, acc, tid, lane, wr, wc);
  float bcol[4];
  #pragma unroll
  for (int ni = 0; ni < 4; ++ni)
    bcol[ni] = bsum[vcx * 128 + wc * 64 + ni * 16 + (lane & 15)];
  int colb = vcx * 128 + wc * 64 + (lane & 15);
  int rowb = mtx * 256 + wr * 64 + ((lane >> 4) << 2);
  #pragma unroll
  for (int mi = 0; mi < 4; ++mi){
    #pragma unroll
    for (int ni = 0; ni < 4; ++ni){
      float b = bcol[ni];
      u32 lo = (u32)f2bf(acc[mi][ni][0] + b) | ((u32)f2bf(acc[mi][ni][1] + b) << 16);
      u32 hi = (u32)f2bf(acc[mi][ni][2] + b) | ((u32)f2bf(acc[mi][ni][3] + b) << 16);
      uint2 pk; pk.x = lo; pk.y = hi;
      *(uint2*)(Xg + (size_t)(colb + ni * 16) * 8192 + rowb + mi * 16) = pk;
    }
  }
}

// ---------------- emit tile: exp-row-sum of Hall[mt] @ Ew[vc]^T + emit_b ----------------
__device__ __forceinline__ void emit_tile(int qi, const u16* __restrict__ Hall,
                                          const u16* __restrict__ Ew,
                                          const float* __restrict__ emit_b,
                                          float* __restrict__ parts,
                                          u32* __restrict__ flagw,
                                          char* sm, int tid, int lane, int w){
  u32 mt = (u32)qi / 250u, vc = (u32)qi % 250u;
  int wr = w >> 1, wc = w & 1;
  // gate: all 64 blocks x 8 waves have published step mt*8+8. Bounded budget.
  if (w == 0){
    u32 tgtv = mt * 8u + 8u;
    u32 budget = 1u << 20;
    const u32* fp = flagw + (lane << 5);
    for (;;){
      uint4 f0, f1;
      asm volatile("global_load_dwordx4 %0, %2, off sc0 sc1\n\t"
                   "global_load_dwordx4 %1, %2, off offset:16 sc0 sc1\n\t"
                   "s_waitcnt vmcnt(0)"
                   : "=v"(f0), "=v"(f1) : "v"(fp) : "memory");
      u32 mn = umin2(umin2(umin2(f0.x, f0.y), umin2(f0.z, f0.w)),
                     umin2(umin2(f1.x, f1.y), umin2(f1.z, f1.w)));
      if (__all((int)(mn >= tgtv)) || !--budget) break;
      __builtin_amdgcn_s_sleep(16);
    }
  }
  __syncthreads();
  const u16* Ab = Hall + 32 * 1024 + (size_t)mt * 256 * 1024;
  const u16* Bb = Ew + (size_t)vc * 128 * 1024;
  f32x4 acc[4][4];
  #pragma unroll
  for (int mi = 0; mi < 4; ++mi)
    #pragma unroll
    for (int ni = 0; ni < 4; ++ni){ f32x4 z = {0.f,0.f,0.f,0.f}; acc[mi][ni] = z; }
  tile_gemm(Ab, Bb, 10, sm, acc, tid, lane, wr, wc);
  float* rs = (float*)(sm + 49152);   // [2][256]
  float eb[4];
  #pragma unroll
  for (int ni = 0; ni < 4; ++ni)
    eb[ni] = emit_b[vc * 128 + wc * 64 + ni * 16 + (lane & 15)];
  #pragma unroll
  for (int mi = 0; mi < 4; ++mi){
    #pragma unroll
    for (int r = 0; r < 4; ++r){
      float s = 0.f;
      #pragma unroll
      for (int ni = 0; ni < 4; ++ni) s += __expf(acc[mi][ni][r] + eb[ni]);
      s += __shfl_xor(s, 1); s += __shfl_xor(s, 2); s += __shfl_xor(s, 4); s += __shfl_xor(s, 8);
      if ((lane & 15) == 0)
        rs[wc * 256 + wr * 64 + mi * 16 + ((lane >> 4) << 2) + r] = s;
    }
  }
  __syncthreads();
  if (tid < 256)
    parts[(size_t)vc * 8192 + (size_t)mt * 256 + tid] = rs[tid] + rs[256 + tid];
  __syncthreads();
}

// ---------------- mega kernel: LSTM recurrence (blocks 0-63) + emit workers -----------
// 512 blocks = 2/CU. Dependency graph ACYCLIC: LSTM -> flagw -> emit.
__launch_bounds__(512, 4)
__global__ void k_mega(const u16* __restrict__ Wc, const u16* __restrict__ Xg,
                       const u16* __restrict__ Ew, const float* __restrict__ emit_b,
                       u16* __restrict__ Hall, float* __restrict__ parts,
                       u32* __restrict__ ctrl){
  __shared__ __align__(16) char smem[65536];
  __shared__ int qshare;
  u32* q2    = ctrl;              // emit tile queue
  u32* flagw = ctrl + 1024;       // [64 blocks][32 u32] ; words 0..7 = per-wave step

  const int tid  = threadIdx.x;
  const int lane = tid & 63;
  const int w    = tid >> 6;
  const int bid  = blockIdx.x;

  if (bid >= 64){
    // -------- worker role: drain emit queue --------
    for (;;){
      if (tid == 0) qshare = (int)__hip_atomic_fetch_add(q2, 1u, __ATOMIC_RELAXED, __HIP_MEMORY_SCOPE_AGENT);
      __syncthreads();
      int qi = qshare;
      __syncthreads();
      if (qi >= 8000) break;
      emit_tile(qi, Hall, Ew, emit_b, parts, flagw, smem, tid, lane, w);
    }
    return;
  }

  // -------- lstm role (blocks 0..63), priority-boosted --------
  __builtin_amdgcn_s_setprio(1);
  const int nc0  = bid << 4;
  const int em   = tid >> 4, en = tid & 15;
  const int arow = lane & 15;
  const int akg  = (lane >> 4) << 3;
  float c = 0.f;
  float* Gp = (float*)smem;   // [8][4][32][16]

  // weights: all 4 gates, K-slice w*128 (h-half of Wc = offset 1024)
  bf16x8 breg[4][4];
  {
    const u16* bp = Wc + (((size_t)(nc0 + arow)) << 11) + 1024 + (w << 7) + akg;
    #pragma unroll
    for (int g = 0; g < 4; ++g)
      #pragma unroll
      for (int kk = 0; kk < 4; ++kk)
        breg[g][kk] = *(const bf16x8*)(bp + (((size_t)g) << 21) + (kk << 5));
  }

  // col-major Xg base for this thread's cell (gate g at +g*1024*8192)
  const u16* xgb = Xg + (size_t)(nc0 + en) * 8192 + em;

  for (int t = 0; t < T_; ++t){
    // 1. per-wave poll: 64 producer-wave flags (blocks 8w..8w+7, waves 0..7)
    {
      const u32* fp = flagw + ((8 * w + (lane >> 3)) << 5) + (lane & 7);
      u32 budget = 1u << 22;
      u32 fv;
      do {
        asm volatile("global_load_dword %0, %1, off sc0 sc1\n\ts_waitcnt vmcnt(0)"
                     : "=v"(fv) : "v"(fp) : "memory");
      } while (!__all((int)(fv >= (u32)t)) && --budget);
    }
    // 2. h fragment loads (sc, L3)
    uint4 a0[4], a1[4];
    {
      const u16* h0 = Hall + (((size_t)t) << 15) + (((size_t)arow) << 10) + (w << 7) + akg;
      const u16* h1 = h0 + 16384;
      #pragma unroll
      for (int kk = 0; kk < 4; ++kk){
        asm volatile("global_load_dwordx4 %0, %1, off offset:%2 sc0 sc1"
                     : "=v"(a0[kk]) : "v"(h0), "n"(kk * 64));
        asm volatile("global_load_dwordx4 %0, %1, off offset:%2 sc0 sc1"
                     : "=v"(a1[kk]) : "v"(h1), "n"(kk * 64));
      }
    }
    // 3. Xg loads (plain cached; produced by k_xgemm before this kernel)
    u16 x0 = xgb[(size_t)t * 32];
    u16 x1 = xgb[1024ull * 8192 + (size_t)t * 32];
    u16 x2 = xgb[2048ull * 8192 + (size_t)t * 32];
    u16 x3 = xgb[3072ull * 8192 + (size_t)t * 32];
    asm volatile("s_waitcnt vmcnt(0)" ::: "memory");
    __builtin_amdgcn_sched_barrier(0);   // rule #18: keep MFMAs below the wait
    __syncthreads();                     // Gp protection (prev iter reads done)

    // 4. MFMA: 4 gates x 2 M-tiles x 4 k-steps
    f32x4 acc[4][2];
    #pragma unroll
    for (int g = 0; g < 4; ++g){ f32x4 z = {0.f,0.f,0.f,0.f}; acc[g][0] = z; acc[g][1] = z; }
    #pragma unroll
    for (int kk = 0; kk < 4; ++kk){
      bf16x8 f0 = __builtin_bit_cast(bf16x8, a0[kk]);
      bf16x8 f1 = __builtin_bit_cast(bf16x8, a1[kk]);
      #pragma unroll
      for (int g = 0; g < 4; ++g){
        acc[g][0] = __builtin_amdgcn_mfma_f32_16x16x32_bf16(f0, breg[g][kk], acc[g][0], 0, 0, 0);
        acc[g][1] = __builtin_amdgcn_mfma_f32_16x16x32_bf16(f1, breg[g][kk], acc[g][1], 0, 0, 0);
      }
    }
    // 5. partials to LDS
    #pragma unroll
    for (int g = 0; g < 4; ++g)
      #pragma unroll
      for (int mt2 = 0; mt2 < 2; ++mt2)
        #pragma unroll
        for (int r = 0; r < 4; ++r){
          int m = ((lane >> 4) << 2) + r + mt2 * 16;
          Gp[((w * 4 + g) * 32 + m) * 16 + (lane & 15)] = acc[g][mt2][r];
        }
    __syncthreads();

    // 6. elementwise (thread = one (em,en) cell), publish h_{t+1}; per-wave flag
    {
      float s0 = bf2f(x0), s1 = bf2f(x1), s2 = bf2f(x2), s3 = bf2f(x3);
      #pragma unroll
      for (int p = 0; p < 8; ++p){
        s0 += Gp[((p * 4 + 0) * 32 + em) * 16 + en];
        s1 += Gp[((p * 4 + 1) * 32 + em) * 16 + en];
        s2 += Gp[((p * 4 + 2) * 32 + em) * 16 + en];
        s3 += Gp[((p * 4 + 3) * 32 + em) * 16 + en];
      }
      float ig = fsig(s0), fg = fsig(s1), gg = ftanh(s2), og = fsig(s3);
      c = fg * c + ig * gg;
      float h = og * ftanh(c);
      u32 hb = (u32)f2bf(h);
      const u16* hp = Hall + (((size_t)(t + 1)) << 15) + (((size_t)em) << 10) + nc0 + en;
      asm volatile("global_store_short %0, %1, off sc0 sc1" :: "v"(hp), "v"(hb) : "memory");
    }
    asm volatile("s_waitcnt vmcnt(0)" ::: "memory");   // wave's 4 h-rows visible
    if (lane == 0){
      u32 fv = (u32)(t + 1);
      asm volatile("global_store_dword %0, %1, off sc0 sc1"
                   :: "v"(flagw + (bid << 5) + w), "v"(fv) : "memory");
    }
  }
  __builtin_amdgcn_s_setprio(0);

  // done with recurrence: help drain emit queue
  for (;;){
    if (tid == 0) qshare = (int)__hip_atomic_fetch_add(q2, 1u, __ATOMIC_RELAXED, __HIP_MEMORY_SCOPE_AGENT);
    __syncthreads();
    int qi = qshare;
    __syncthreads();
    if (qi >= 8000) break;
    emit_tile(qi, Hall, Ew, emit_b, parts, flagw, smem, tid, lane, w);
  }
}

// ---------------- target logit per row ----------------
__global__ void k_target(const u16* __restrict__ Hall, const u16* __restrict__ Ew,
                         const int* __restrict__ words, const float* __restrict__ emit_b,
                         float* __restrict__ tgt){
  int row  = blockIdx.x * 4 + (threadIdx.x >> 6);
  int lane = threadIdx.x & 63;
  int t = row >> 5, b = row & 31;
  int wd = words[b * T_ + t];
  const bf16x8* ha = (const bf16x8*)(Hall + (size_t)(row + 32) * 1024 + lane * 16);
  const bf16x8* wa = (const bf16x8*)(Ew + (size_t)wd * 1024 + lane * 16);
  float s = 0.f;
  #pragma unroll
  for (int p = 0; p < 2; ++p){
    bf16x8 av = ha[p], wv = wa[p];
    #pragma unroll
    for (int i = 0; i < 8; ++i) s += bf2f((u16)av[i]) * bf2f((u16)wv[i]);
  }
  s += __shfl_xor(s, 32); s += __shfl_xor(s, 16); s += __shfl_xor(s, 8);
  s += __shfl_xor(s, 4);  s += __shfl_xor(s, 2);  s += __shfl_xor(s, 1);
  if (lane == 0) tgt[row] = s + emit_b[wd];
}

// ---------------- finalize ----------------
__global__ void k_final(const float* __restrict__ partials, const float* __restrict__ tgt,
                        float* __restrict__ out){
  int i = blockIdx.x * 256 + threadIdx.x;
  float s = 0.f;
  for (int vcb = 0; vcb < 250; ++vcb) s += partials[(size_t)vcb * 8192 + i];
  out[i] = tgt[i] - logf(s);
}

extern "C" void kernel_launch(void* const* d_in, const int* in_sizes, int n_in,
                              void* d_out, int out_size, void* d_ws, size_t ws_size,
                              hipStream_t stream){
  const int*   words = (const int*)d_in[0];
  const float* embed = (const float*)d_in[1];
  const float* wih   = (const float*)d_in[2];
  const float* whh   = (const float*)d_in[3];
  const float* bih   = (const float*)d_in[4];
  const float* bhh   = (const float*)d_in[5];
  const float* emw   = (const float*)d_in[6];
  const float* emb_b = (const float*)d_in[7];
  float* out = (float*)d_out;

  // workspace layout (bytes)
  char* ws = (char*)d_ws;
  u16* Wc   = (u16*)ws;                          // 16,777,216 B
  u16* Ew   = (u16*)(ws + 16777216);             // 65,536,000 B
  u16* X    = (u16*)(ws + 82313216);             // 16,777,216 B
  u16* Hall = (u16*)(ws + 99090432);             // 16,842,752 B (257*32*1024 u16)
  u16* Xg   = (u16*)(ws + 115933184);            // 67,108,864 B (col-major [4096][8192] u16)
  float* bsum = (float*)(ws + 183042048);        // 16,384 B
  float* tgt  = (float*)(ws + 183058432);        // 32,768 B
  float* parts= (float*)(ws + 183091200);        // 8,192,000 B
  u32*  ctrl  = (u32*)(ws + 191283200);          // 16,384 B
  size_t need = 191283200ULL + 16384ULL;
  if (ws_size < need) return;  // fail loudly via validation

  hipMemsetAsync(ctrl, 0, 16384, stream);
  hipMemsetAsync(Hall, 0, 32 * 1024 * 2, stream);   // h_{-1} = 0

  k_prep_wc  <<<8192,  256, 0, stream>>>(wih, whh, Wc);
  k_prep_ew  <<<32000, 256, 0, stream>>>(emw, Ew);
  k_prep_bsum<<<16,    256, 0, stream>>>(bih, bhh, bsum);
  k_gather_x <<<8192,  256, 0, stream>>>(words, embed, X);
  k_xgemm    <<<1024,  512, 0, stream>>>(X, Wc, bsum, Xg);
  k_mega     <<<512,   512, 0, stream>>>(Wc, Xg, Ew, emb_b, Hall, parts, ctrl);
  k_target   <<<2048,  256, 0, stream>>>(Hall, Ew, words, emb_b, tgt);
  k_final    <<<32,    256, 0, stream>>>(parts, tgt, out);
}

// Round 8
// 1489.273 us; speedup vs baseline: 1.8214x; 1.8214x over previous
//
#include <hip/hip_runtime.h>
#include <stdint.h>

#define B_ 32
#define T_ 256
#define E_ 1024
#define H_ 1024
#define V_ 32000

typedef unsigned short u16;
typedef unsigned int   u32;
typedef unsigned long long u64;

typedef __attribute__((ext_vector_type(8))) short bf16x8;
typedef __attribute__((ext_vector_type(4))) float f32x4;

__device__ __forceinline__ float bf2f(u16 u){ u32 x = ((u32)u) << 16; return __uint_as_float(x); }
__device__ __forceinline__ u16  f2bf(float f){
  u32 x = __float_as_uint(f);
  u32 r = (x + 0x7fffu + ((x >> 16) & 1u)) >> 16;
  return (u16)r;
}
__device__ __forceinline__ float fsig(float x){ return 1.f / (1.f + __expf(-x)); }
__device__ __forceinline__ float ftanh(float x){
  float e = __expf(2.f * x);
  return 1.f - 2.f / (e + 1.f);
}

__device__ __forceinline__ void gload_lds16(const void* g, void* l){
  __builtin_amdgcn_global_load_lds((const __attribute__((address_space(1))) unsigned int*)g,
                                   (__attribute__((address_space(3))) unsigned int*)l, 16, 0, 0);
}

// ---------------- prep kernels ----------------
__global__ void k_prep_wc(const float* __restrict__ wih, const float* __restrict__ whh,
                          u16* __restrict__ Wc){
  int i = blockIdx.x * 256 + threadIdx.x;
  int r = i >> 9; int k4 = (i & 511) << 2;
  const float* src = (k4 < 1024) ? (wih + (size_t)r * 1024 + k4)
                                 : (whh + (size_t)r * 1024 + (k4 - 1024));
  float4 v = *(const float4*)src;
  u64 pk = (u64)f2bf(v.x) | ((u64)f2bf(v.y) << 16) | ((u64)f2bf(v.z) << 32) | ((u64)f2bf(v.w) << 48);
  *(u64*)(Wc + (size_t)r * 2048 + k4) = pk;
}

__global__ void k_prep_ew(const float* __restrict__ src, u16* __restrict__ dst){
  size_t i = (size_t)(blockIdx.x * 256 + threadIdx.x) * 4;
  float4 v = *(const float4*)(src + i);
  u64 pk = (u64)f2bf(v.x) | ((u64)f2bf(v.y) << 16) | ((u64)f2bf(v.z) << 32) | ((u64)f2bf(v.w) << 48);
  *(u64*)(dst + i) = pk;
}

__global__ void k_prep_bsum(const float* __restrict__ bih, const float* __restrict__ bhh,
                            float* __restrict__ bsum){
  int i = blockIdx.x * 256 + threadIdx.x;
  bsum[i] = bih[i] + bhh[i];
}

__global__ void k_gather_x(const int* __restrict__ words, const float* __restrict__ embed,
                           u16* __restrict__ X){
  int row = blockIdx.x;                         // t*32 + b
  int t = row >> 5, b = row & 31;
  int wd = words[b * T_ + t];
  const float* src = embed + (size_t)wd * E_;
  u16* dst = X + (size_t)row * E_;
  int e = threadIdx.x * 4;
  float4 v = *(const float4*)(src + e);
  u64 pk = (u64)f2bf(v.x) | ((u64)f2bf(v.y) << 16) | ((u64)f2bf(v.z) << 32) | ((u64)f2bf(v.w) << 48);
  *(u64*)(dst + e) = pk;
}

// ---------------- shared 256x128 GEMM tile core, DOUBLE-BUFFERED ----------------
// A: 256 rows, stride 1024 u16. B: 128 rows, stride (1<<blog2) u16. K = 1024.
// LDS: buf[p] at sm + p*24576 (As 16K + Bs 8K). Counted vmcnt(3) keeps the next
// K-step's 3 global_load_lds in flight across the barriers (T3/T4 minimum).
__device__ __forceinline__ void stage_tile(const u16* __restrict__ Ab, const u16* __restrict__ Bb,
                                           int blog2, char* buf, int kk, int tid){
  char* As = buf;
  char* Bs = buf + 16384;
  int u0 = tid, r0 = u0 >> 2, s0 = (u0 & 3) ^ ((r0 >> 1) & 3);
  gload_lds16(Ab + (((size_t)r0) << 10) + kk * 32 + s0 * 8, As + (size_t)u0 * 16);
  int u1 = 512 + tid, r1 = u1 >> 2, s1 = (u1 & 3) ^ ((r1 >> 1) & 3);
  gload_lds16(Ab + (((size_t)r1) << 10) + kk * 32 + s1 * 8, As + (size_t)u1 * 16);
  int r2 = tid >> 2, s2 = (tid & 3) ^ ((r2 >> 1) & 3);
  gload_lds16(Bb + (((size_t)r2) << blog2) + kk * 32 + s2 * 8, Bs + (size_t)tid * 16);
}

__device__ __forceinline__ void tile_gemm(const u16* __restrict__ Ab, const u16* __restrict__ Bb,
                                          int blog2, char* sm, f32x4 (&acc)[4][4],
                                          int tid, int lane, int wr, int wc){
  stage_tile(Ab, Bb, blog2, sm, 0, tid);
  #pragma unroll 2
  for (int kk = 0; kk < 32; ++kk){
    char* cur = sm + (size_t)(kk & 1) * 24576;
    if (kk < 31){
      stage_tile(Ab, Bb, blog2, sm + (size_t)((kk + 1) & 1) * 24576, kk + 1, tid);
      asm volatile("s_waitcnt vmcnt(3)" ::: "memory");
    } else {
      asm volatile("s_waitcnt vmcnt(0)" ::: "memory");
    }
    __builtin_amdgcn_s_barrier();     // all waves' tile-kk loads have landed
    __builtin_amdgcn_sched_barrier(0);
    char* As = cur;
    char* Bs = cur + 16384;
    bf16x8 af[4], bfr[4];
    #pragma unroll
    for (int mi = 0; mi < 4; ++mi){
      int r = wr * 64 + mi * 16 + (lane & 15);
      u32 byte = ((u32)r << 6) + (((u32)lane >> 4) << 4);
      byte ^= (u32)(r & 6) << 3;
      af[mi] = *(const bf16x8*)(As + byte);
    }
    #pragma unroll
    for (int ni = 0; ni < 4; ++ni){
      int r = wc * 64 + ni * 16 + (lane & 15);
      u32 byte = ((u32)r << 6) + (((u32)lane >> 4) << 4);
      byte ^= (u32)(r & 6) << 3;
      bfr[ni] = *(const bf16x8*)(Bs + byte);
    }
    #pragma unroll
    for (int mi = 0; mi < 4; ++mi)
      #pragma unroll
      for (int ni = 0; ni < 4; ++ni)
        acc[mi][ni] = __builtin_amdgcn_mfma_f32_16x16x32_bf16(af[mi], bfr[ni], acc[mi][ni], 0, 0, 0);
    __builtin_amdgcn_s_barrier();     // ds_reads of cur complete before restage at kk+2
  }
}

// ---------------- k_xgemm: Xg (COL-MAJOR [4096][8192]) = X @ Wih^T + bsum -----------
__launch_bounds__(512, 2)
__global__ void k_xgemm(const u16* __restrict__ X, const u16* __restrict__ Wc,
                        const float* __restrict__ bsum, u16* __restrict__ Xg){
  __shared__ __align__(16) char smem[49152];
  const int tid = threadIdx.x, lane = tid & 63, w = tid >> 6;
  const int wr = w >> 1, wc = w & 1;
  const int mtx = blockIdx.x >> 5, vcx = blockIdx.x & 31;
  const u16* Ab = X + (size_t)mtx * 256 * 1024;
  const u16* Bb = Wc + (size_t)vcx * 128 * 2048;
  f32x4 acc[4][4];
  #pragma unroll
  for (int mi = 0; mi < 4; ++mi)
    #pragma unroll
    for (int ni = 0; ni < 4; ++ni){ f32x4 z = {0.f,0.f,0.f,0.f}; acc[mi][ni] = z; }
  tile_gemm(Ab, Bb, 11, smem, acc, tid, lane, wr, wc);
  float bcol[4];
  #pragma unroll
  for (int ni = 0; ni < 4; ++ni)
    bcol[ni] = bsum[vcx * 128 + wc * 64 + ni * 16 + (lane & 15)];
  int colb = vcx * 128 + wc * 64 + (lane & 15);
  int rowb = mtx * 256 + wr * 64 + ((lane >> 4) << 2);
  #pragma unroll
  for (int mi = 0; mi < 4; ++mi){
    #pragma unroll
    for (int ni = 0; ni < 4; ++ni){
      float b = bcol[ni];
      u32 lo = (u32)f2bf(acc[mi][ni][0] + b) | ((u32)f2bf(acc[mi][ni][1] + b) << 16);
      u32 hi = (u32)f2bf(acc[mi][ni][2] + b) | ((u32)f2bf(acc[mi][ni][3] + b) << 16);
      uint2 pk; pk.x = lo; pk.y = hi;
      *(uint2*)(Xg + (size_t)(colb + ni * 16) * 8192 + rowb + mi * 16) = pk;
    }
  }
}

// ---------------- emit tile: exp-row-sum of Hall[mt] @ Ew[vc]^T + emit_b ----------------
__device__ __forceinline__ void emit_tile(int qi, const u16* __restrict__ Hall,
                                          const u16* __restrict__ Ew,
                                          const float* __restrict__ emit_b,
                                          float* __restrict__ parts,
                                          u32* __restrict__ flags,
                                          char* sm, int tid, int lane, int w){
  u32 mt = (u32)qi / 250u, vc = (u32)qi % 250u;
  int wr = w >> 1, wc = w & 1;
  // gate: all 64 producer flags >= mt*8+8 (wave 0 polls, block barrier after).
  if (w == 0){
    u32 tgtv = mt * 8u + 8u;
    u32 budget = 1u << 20;
    const u32* fp = flags + (lane << 5);
    for (;;){
      u32 fv;
      asm volatile("global_load_dword %0, %1, off sc0 sc1\n\ts_waitcnt vmcnt(0)"
                   : "=v"(fv) : "v"(fp) : "memory");
      if (__all((int)(fv >= tgtv)) || !--budget) break;
      __builtin_amdgcn_s_sleep(16);
    }
  }
  __syncthreads();
  const u16* Ab = Hall + 32 * 1024 + (size_t)mt * 256 * 1024;
  const u16* Bb = Ew + (size_t)vc * 128 * 1024;
  f32x4 acc[4][4];
  #pragma unroll
  for (int mi = 0; mi < 4; ++mi)
    #pragma unroll
    for (int ni = 0; ni < 4; ++ni){ f32x4 z = {0.f,0.f,0.f,0.f}; acc[mi][ni] = z; }
  tile_gemm(Ab, Bb, 10, sm, acc, tid, lane, wr, wc);
  float* rs = (float*)(sm + 49152);   // [2][256]
  float eb[4];
  #pragma unroll
  for (int ni = 0; ni < 4; ++ni)
    eb[ni] = emit_b[vc * 128 + wc * 64 + ni * 16 + (lane & 15)];
  #pragma unroll
  for (int mi = 0; mi < 4; ++mi){
    #pragma unroll
    for (int r = 0; r < 4; ++r){
      float s = 0.f;
      #pragma unroll
      for (int ni = 0; ni < 4; ++ni) s += __expf(acc[mi][ni][r] + eb[ni]);
      s += __shfl_xor(s, 1); s += __shfl_xor(s, 2); s += __shfl_xor(s, 4); s += __shfl_xor(s, 8);
      if ((lane & 15) == 0)
        rs[wc * 256 + wr * 64 + mi * 16 + ((lane >> 4) << 2) + r] = s;
    }
  }
  __syncthreads();
  if (tid < 256)
    parts[(size_t)vc * 8192 + (size_t)mt * 256 + tid] = rs[tid] + rs[256 + tid];
  __syncthreads();
}

// ---------------- mega kernel: LSTM recurrence (blocks 0-63) + emit workers -----------
// 256 blocks = 1/CU (recurrence CUs stay isolated). ACYCLIC: LSTM -> flags -> emit.
__launch_bounds__(512, 2)
__global__ void k_mega(const u16* __restrict__ Wc, const u16* __restrict__ Xg,
                       const u16* __restrict__ Ew, const float* __restrict__ emit_b,
                       u16* __restrict__ Hall, float* __restrict__ parts,
                       u32* __restrict__ ctrl){
  __shared__ __align__(16) char smem[65536];
  __shared__ int qshare;
  u32* q2    = ctrl;              // emit tile queue
  u32* flags = ctrl + 1024;       // [64] stride-32 u32 (128B apart)

  const int tid  = threadIdx.x;
  const int lane = tid & 63;
  const int w    = tid >> 6;
  const int bid  = blockIdx.x;

  if (bid >= 64){
    // -------- worker role: drain emit queue --------
    for (;;){
      if (tid == 0) qshare = (int)__hip_atomic_fetch_add(q2, 1u, __ATOMIC_RELAXED, __HIP_MEMORY_SCOPE_AGENT);
      __syncthreads();
      int qi = qshare;
      __syncthreads();
      if (qi >= 8000) break;
      emit_tile(qi, Hall, Ew, emit_b, parts, flags, smem, tid, lane, w);
    }
    return;
  }

  // -------- lstm role (blocks 0..63) --------
  const int nc0  = bid << 4;
  const int em   = tid >> 4, en = tid & 15;
  const int arow = lane & 15;
  const int akg  = (lane >> 4) << 3;
  float c = 0.f;
  float* Gp = (float*)smem;   // [8][4][32][16]

  // weights: all 4 gates, K-slice w*128 (h-half of Wc = offset 1024)
  bf16x8 breg[4][4];
  {
    const u16* bp = Wc + (((size_t)(nc0 + arow)) << 11) + 1024 + (w << 7) + akg;
    #pragma unroll
    for (int g = 0; g < 4; ++g)
      #pragma unroll
      for (int kk = 0; kk < 4; ++kk)
        breg[g][kk] = *(const bf16x8*)(bp + (((size_t)g) << 21) + (kk << 5));
  }

  // col-major Xg base for this thread's cell (gate g at +g*1024*8192)
  const u16* xgb = Xg + (size_t)(nc0 + en) * 8192 + em;

  for (int t = 0; t < T_; ++t){
    // 1. flag poll: wave w consumes h cols [w*128, w*128+128) = blocks 8w..8w+7
    {
      const u32* fp = flags + ((8 * w + (lane & 7)) << 5);
      u32 budget = 1u << 22;
      u32 fv;
      do {
        asm volatile("global_load_dword %0, %1, off sc0 sc1\n\ts_waitcnt vmcnt(0)"
                     : "=v"(fv) : "v"(fp) : "memory");
      } while (!__all((int)(fv >= (u32)t)) && --budget);
    }
    // 2. h fragment loads (sc, L3)
    uint4 a0[4], a1[4];
    {
      const u16* h0 = Hall + (((size_t)t) << 15) + (((size_t)arow) << 10) + (w << 7) + akg;
      const u16* h1 = h0 + 16384;
      #pragma unroll
      for (int kk = 0; kk < 4; ++kk){
        asm volatile("global_load_dwordx4 %0, %1, off offset:%2 sc0 sc1"
                     : "=v"(a0[kk]) : "v"(h0), "n"(kk * 64));
        asm volatile("global_load_dwordx4 %0, %1, off offset:%2 sc0 sc1"
                     : "=v"(a1[kk]) : "v"(h1), "n"(kk * 64));
      }
    }
    // 3. Xg loads (plain cached; produced by k_xgemm before this kernel)
    u16 x0 = xgb[(size_t)t * 32];
    u16 x1 = xgb[1024ull * 8192 + (size_t)t * 32];
    u16 x2 = xgb[2048ull * 8192 + (size_t)t * 32];
    u16 x3 = xgb[3072ull * 8192 + (size_t)t * 32];
    asm volatile("s_waitcnt vmcnt(0)" ::: "memory");
    __builtin_amdgcn_sched_barrier(0);   // rule #18: keep MFMAs below the wait

    // 4. MFMA: 4 gates x 2 M-tiles x 4 k-steps
    f32x4 acc[4][2];
    #pragma unroll
    for (int g = 0; g < 4; ++g){ f32x4 z = {0.f,0.f,0.f,0.f}; acc[g][0] = z; acc[g][1] = z; }
    #pragma unroll
    for (int kk = 0; kk < 4; ++kk){
      bf16x8 f0 = __builtin_bit_cast(bf16x8, a0[kk]);
      bf16x8 f1 = __builtin_bit_cast(bf16x8, a1[kk]);
      #pragma unroll
      for (int g = 0; g < 4; ++g){
        acc[g][0] = __builtin_amdgcn_mfma_f32_16x16x32_bf16(f0, breg[g][kk], acc[g][0], 0, 0, 0);
        acc[g][1] = __builtin_amdgcn_mfma_f32_16x16x32_bf16(f1, breg[g][kk], acc[g][1], 0, 0, 0);
      }
    }
    // 5. partials to LDS
    #pragma unroll
    for (int g = 0; g < 4; ++g)
      #pragma unroll
      for (int mt2 = 0; mt2 < 2; ++mt2)
        #pragma unroll
        for (int r = 0; r < 4; ++r){
          int m = ((lane >> 4) << 2) + r + mt2 * 16;
          Gp[((w * 4 + g) * 32 + m) * 16 + (lane & 15)] = acc[g][mt2][r];
        }
    __syncthreads();

    // 6. elementwise (thread = one (em,en) cell), publish h_{t+1}
    {
      float s0 = bf2f(x0), s1 = bf2f(x1), s2 = bf2f(x2), s3 = bf2f(x3);
      #pragma unroll
      for (int p = 0; p < 8; ++p){
        s0 += Gp[((p * 4 + 0) * 32 + em) * 16 + en];
        s1 += Gp[((p * 4 + 1) * 32 + em) * 16 + en];
        s2 += Gp[((p * 4 + 2) * 32 + em) * 16 + en];
        s3 += Gp[((p * 4 + 3) * 32 + em) * 16 + en];
      }
      float ig = fsig(s0), fg = fsig(s1), gg = ftanh(s2), og = fsig(s3);
      c = fg * c + ig * gg;
      float h = og * ftanh(c);
      u32 hb = (u32)f2bf(h);
      const u16* hp = Hall + (((size_t)(t + 1)) << 15) + (((size_t)em) << 10) + nc0 + en;
      asm volatile("global_store_short %0, %1, off sc0 sc1" :: "v"(hp), "v"(hb) : "memory");
    }
    asm volatile("s_waitcnt vmcnt(0)" ::: "memory");
    __syncthreads();
    if (tid == 0){
      u32 fv = (u32)(t + 1);
      asm volatile("global_store_dword %0, %1, off sc0 sc1"
                   :: "v"(flags + (bid << 5)), "v"(fv) : "memory");
    }
  }

  // done with recurrence: help drain emit queue
  for (;;){
    if (tid == 0) qshare = (int)__hip_atomic_fetch_add(q2, 1u, __ATOMIC_RELAXED, __HIP_MEMORY_SCOPE_AGENT);
    __syncthreads();
    int qi = qshare;
    __syncthreads();
    if (qi >= 8000) break;
    emit_tile(qi, Hall, Ew, emit_b, parts, flags, smem, tid, lane, w);
  }
}

// ---------------- target logit per row ----------------
__global__ void k_target(const u16* __restrict__ Hall, const u16* __restrict__ Ew,
                         const int* __restrict__ words, const float* __restrict__ emit_b,
                         float* __restrict__ tgt){
  int row  = blockIdx.x * 4 + (threadIdx.x >> 6);
  int lane = threadIdx.x & 63;
  int t = row >> 5, b = row & 31;
  int wd = words[b * T_ + t];
  const bf16x8* ha = (const bf16x8*)(Hall + (size_t)(row + 32) * 1024 + lane * 16);
  const bf16x8* wa = (const bf16x8*)(Ew + (size_t)wd * 1024 + lane * 16);
  float s = 0.f;
  #pragma unroll
  for (int p = 0; p < 2; ++p){
    bf16x8 av = ha[p], wv = wa[p];
    #pragma unroll
    for (int i = 0; i < 8; ++i) s += bf2f((u16)av[i]) * bf2f((u16)wv[i]);
  }
  s += __shfl_xor(s, 32); s += __shfl_xor(s, 16); s += __shfl_xor(s, 8);
  s += __shfl_xor(s, 4);  s += __shfl_xor(s, 2);  s += __shfl_xor(s, 1);
  if (lane == 0) tgt[row] = s + emit_b[wd];
}

// ---------------- finalize ----------------
__global__ void k_final(const float* __restrict__ partials, const float* __restrict__ tgt,
                        float* __restrict__ out){
  int i = blockIdx.x * 256 + threadIdx.x;
  float s = 0.f;
  for (int vcb = 0; vcb < 250; ++vcb) s += partials[(size_t)vcb * 8192 + i];
  out[i] = tgt[i] - logf(s);
}

extern "C" void kernel_launch(void* const* d_in, const int* in_sizes, int n_in,
                              void* d_out, int out_size, void* d_ws, size_t ws_size,
                              hipStream_t stream){
  const int*   words = (const int*)d_in[0];
  const float* embed = (const float*)d_in[1];
  const float* wih   = (const float*)d_in[2];
  const float* whh   = (const float*)d_in[3];
  const float* bih   = (const float*)d_in[4];
  const float* bhh   = (const float*)d_in[5];
  const float* emw   = (const float*)d_in[6];
  const float* emb_b = (const float*)d_in[7];
  float* out = (float*)d_out;

  // workspace layout (bytes)
  char* ws = (char*)d_ws;
  u16* Wc   = (u16*)ws;                          // 16,777,216 B
  u16* Ew   = (u16*)(ws + 16777216);             // 65,536,000 B
  u16* X    = (u16*)(ws + 82313216);             // 16,777,216 B
  u16* Hall = (u16*)(ws + 99090432);             // 16,842,752 B (257*32*1024 u16)
  u16* Xg   = (u16*)(ws + 115933184);            // 67,108,864 B (col-major [4096][8192] u16)
  float* bsum = (float*)(ws + 183042048);        // 16,384 B
  float* tgt  = (float*)(ws + 183058432);        // 32,768 B
  float* parts= (float*)(ws + 183091200);        // 8,192,000 B
  u32*  ctrl  = (u32*)(ws + 191283200);          // 16,384 B
  size_t need = 191283200ULL + 16384ULL;
  if (ws_size < need) return;  // fail loudly via validation

  hipMemsetAsync(ctrl, 0, 16384, stream);
  hipMemsetAsync(Hall, 0, 32 * 1024 * 2, stream);   // h_{-1} = 0

  k_prep_wc  <<<8192,  256, 0, stream>>>(wih, whh, Wc);
  k_prep_ew  <<<32000, 256, 0, stream>>>(emw, Ew);
  k_prep_bsum<<<16,    256, 0, stream>>>(bih, bhh, bsum);
  k_gather_x <<<8192,  256, 0, stream>>>(words, embed, X);
  k_xgemm    <<<1024,  512, 0, stream>>>(X, Wc, bsum, Xg);
  k_mega     <<<256,   512, 0, stream>>>(Wc, Xg, Ew, emb_b, Hall, parts, ctrl);
  k_target   <<<2048,  256, 0, stream>>>(Hall, Ew, words, emb_b, tgt);
  k_final    <<<32,    256, 0, stream>>>(parts, tgt, out);
}